// Round 8
// baseline (363.862 us; speedup 1.0000x reference)
//
#include <hip/hip_runtime.h>
#include <math.h>
#include <float.h>

#define HW 4096
#define CHW 262144
#define NTOK 65536
#define NELEM 4194304

// ws float offsets
#define WS_LOSS 0        // 512 floats
#define WS_STD  512      // 64
#define WS_EE   576      // 1024 (exact fp32 row norms)
#define WS_E2   1600     // 131072 ushorts: codebook hi/lo, frag-contiguous per 64-code tile

#define EPSM 2.0e-3f     // ambiguity margin (>=13x rigorous error bound)

typedef __attribute__((ext_vector_type(8))) short bf16x8;
typedef __attribute__((ext_vector_type(4))) float f32x4;

__device__ __forceinline__ unsigned short f2bf(float x) {
  unsigned u = __float_as_uint(x);
  u += 0x7FFFu + ((u >> 16) & 1u);
  return (unsigned short)(u >> 16);
}
__device__ __forceinline__ float bf2f(unsigned short h) {
  return __uint_as_float(((unsigned)h) << 16);
}
__device__ __forceinline__ void gload_lds16(const unsigned short* g, unsigned short* l) {
  __builtin_amdgcn_global_load_lds(
      (const __attribute__((address_space(1))) unsigned int*)g,
      (__attribute__((address_space(3))) unsigned int*)l, 16, 0, 0);
}

// ---------------- k_pre: blocks 0..63 std, 64..79 codebook decompose+swizzle ----------------
__global__ __launch_bounds__(1024) void k_pre(const float* __restrict__ z,
                                              const float* __restrict__ emb,
                                              float* __restrict__ stdv,
                                              unsigned short* __restrict__ e2g,
                                              float* __restrict__ eeg) {
  __shared__ double rs[16], rs2[16];
  int tid = threadIdx.x;
  int blk = blockIdx.x;
  if (blk < 64) {
    // per-channel std (ddof=1) — bit-identical to validated rounds
    int c = blk;
    double s = 0.0, s2 = 0.0;
    const float* base = z + c * HW;
    #pragma unroll 4
    for (int jj = 0; jj < 16; ++jj) {
      int f = tid + (jj << 10);
      int b = f >> 10, off4 = f & 1023;
      float4 v = *(const float4*)(base + (size_t)b * CHW + (off4 << 2));
      s  += (double)v.x + (double)v.y + (double)v.z + (double)v.w;
      s2 += (double)v.x * v.x + (double)v.y * v.y + (double)v.z * v.z + (double)v.w * v.w;
    }
    for (int o = 32; o > 0; o >>= 1) {
      s += __shfl_down(s, o, 64);
      s2 += __shfl_down(s2, o, 64);
    }
    int wv = tid >> 6, ln = tid & 63;
    if (ln == 0) { rs[wv] = s; rs2[wv] = s2; }
    __syncthreads();
    if (tid == 0) {
      double S = 0.0, S2 = 0.0;
      #pragma unroll
      for (int w = 0; w < 16; ++w) { S += rs[w]; S2 += rs2[w]; }
      const double N = (double)NTOK;
      double var = (S2 - S * S / N) / (N - 1.0);
      float sd = (float)sqrt(var);
      stdv[c] = fmaxf(sd, 1e-5f);
    }
  } else {
    // 64 codes/tile: bf16 hi|lo decompose into frag-contiguous tile layout
    // e2g[ct][jH(4)][cH(4)][jL(4)][cL(16)][8]  (ushort strides 2048/512/128/8)
    int ct = blk - 64;
    int k0 = ct << 6;
    int code = tid >> 4, c4 = tid & 15;
    float4 v = *(const float4*)(emb + (size_t)((k0 + code) << 6) + (c4 << 2));
    unsigned short h0 = f2bf(v.x), h1 = f2bf(v.y), h2 = f2bf(v.z), h3 = f2bf(v.w);
    unsigned short l0 = f2bf(v.x - bf2f(h0)), l1 = f2bf(v.y - bf2f(h1));
    unsigned short l2 = f2bf(v.z - bf2f(h2)), l3 = f2bf(v.w - bf2f(h3));
    int jL = (c4 >> 1) & 3;
    int e = (c4 & 1) << 2;
    int cH = code >> 4, cL = code & 15;
    size_t base = (size_t)ct * 8192 + cH * 512 + jL * 128 + cL * 8 + e;
    int jHh = c4 >> 3;          // hi chunks j=c4>>1 in 0..7 -> jH 0..1
    *(uint2*)(e2g + base + (size_t)jHh * 2048) =
        make_uint2((unsigned)h0 | ((unsigned)h1 << 16), (unsigned)h2 | ((unsigned)h3 << 16));
    *(uint2*)(e2g + base + (size_t)(2 + jHh) * 2048) =
        make_uint2((unsigned)l0 | ((unsigned)l1 << 16), (unsigned)l2 | ((unsigned)l3 << 16));
    if (tid < 64) {
      const float* er = emb + (size_t)((k0 + tid) << 6);
      float s = 0.f;
      #pragma unroll
      for (int c = 0; c < 64; ++c) s = fmaf(er[c], er[c], s);
      eeg[k0 + tid] = s;
    }
  }
}

// ---------------- main kernel: MFMA argmin, conflict-free frag layout, DMA-staged B ----------------
__global__ __launch_bounds__(256, 2) void k_vq(
    const float* __restrict__ z_e, const float* __restrict__ emb,
    const float* __restrict__ stdv, const float* __restrict__ eeg,
    const unsigned short* __restrict__ e2g,
    float* __restrict__ out_zq, float* __restrict__ out_idx,
    float* __restrict__ loss_part) {
  __shared__ unsigned short A2[16384];   // 32 KB: z hi/lo frag-contiguous
  __shared__ unsigned short B2[16384];   // 32 KB: two 16 KB code-tile buffers
  // scratch aliased onto A2 after the MFMA loop (A2 dead then):
  float* mbd = (float*)A2;               // [2*128]
  float* msec = (float*)A2 + 256;        // [2*128]
  int*   mbk = (int*)A2 + 512;           // [2*128]
  int*   skf = (int*)A2 + 768;           // [128]
  int*   ambList = (int*)A2 + 896;       // [128]
  int*   ambN = (int*)A2 + 1024;
  float* sred = (float*)A2 + 1028;       // [4]

  int tid = threadIdx.x;
  int lane = tid & 63;
  int wv = tid >> 6;
  int blk = blockIdx.x;            // 512 blocks
  int b = blk >> 5;
  int s0 = (blk & 31) << 7;        // 128 contiguous spatial positions

  // ---- stage A: normalize (IEEE div, bit-exact) + hi/lo decompose, frag layout ----
  // A2[jH(4)][tH(8)][jL(4)][tL(16)][8]: ushort strides 4096/512/128/8
  {
    int tok = tid >> 1, half = tid & 1;
    const float* zsrc = z_e + (size_t)b * CHW + (size_t)(half << 5) * HW + s0 + tok;
    unsigned hw_[16], lw_[16];
    #pragma unroll
    for (int cc = 0; cc < 32; ++cc) {
      float v = zsrc[(size_t)cc * HW] / stdv[(half << 5) + cc];
      unsigned short h = f2bf(v);
      unsigned short l = f2bf(v - bf2f(h));
      if (cc & 1) { hw_[cc >> 1] |= ((unsigned)h) << 16; lw_[cc >> 1] |= ((unsigned)l) << 16; }
      else        { hw_[cc >> 1] = h;                    lw_[cc >> 1] = l; }
    }
    int tH = tok >> 4, tL = tok & 15;
    int base = tH * 512 + tL * 8;
    #pragma unroll
    for (int jj = 0; jj < 4; ++jj) {
      *(uint4*)(A2 + half * 4096 + base + jj * 128) =
          make_uint4(hw_[4 * jj], hw_[4 * jj + 1], hw_[4 * jj + 2], hw_[4 * jj + 3]);
      *(uint4*)(A2 + (2 + half) * 4096 + base + jj * 128) =
          make_uint4(lw_[4 * jj], lw_[4 * jj + 1], lw_[4 * jj + 2], lw_[4 * jj + 3]);
    }
  }

  int quad = lane >> 4, l15 = lane & 15;
  int wt = wv >> 1, wc = wv & 1;

  float bd[16], sec[16];
  int bk[16];
  #pragma unroll
  for (int i = 0; i < 16; ++i) { bd[i] = FLT_MAX; sec[i] = FLT_MAX; bk[i] = 0; }

  // DMA tile 0 into buffer 0 (4 rounds x 1 KB per wave, lane*16B contiguous)
  {
    const unsigned short* gsrc = e2g + wv * 512 + (lane << 3);
    unsigned short* ldst = B2 + wv * 512;
    #pragma unroll
    for (int rr = 0; rr < 4; ++rr)
      gload_lds16(gsrc + rr * 2048, ldst + rr * 2048);
  }

  // slab plan: dot2 = zh*eh + zl*eh + zh*el  (K'=192)
  const int aJH[6] = {0, 1, 2, 3, 0, 1};
  const int bJH[6] = {0, 1, 0, 1, 2, 3};

  for (int ct = 0; ct < 16; ++ct) {
    __syncthreads();   // drains DMA(ct) [+A2 writes on first iter]; frees other buf
    const unsigned short* bb = B2 + (ct & 1) * 8192;
    if (ct < 15) {     // DMA next tile; overlaps compute, drained at next barrier
      const unsigned short* gsrc = e2g + (size_t)(ct + 1) * 8192 + wv * 512 + (lane << 3);
      unsigned short* ldst = B2 + ((ct + 1) & 1) * 8192 + wv * 512;
      #pragma unroll
      for (int rr = 0; rr < 4; ++rr)
        gload_lds16(gsrc + rr * 2048, ldst + rr * 2048);
    }

    f32x4 acc[4][2];
    #pragma unroll
    for (int mt = 0; mt < 4; ++mt) { acc[mt][0] = (f32x4)(0.f); acc[mt][1] = (f32x4)(0.f); }

    #pragma unroll
    for (int s = 0; s < 6; ++s) {
      bf16x8 af[4], bfr[2];
      #pragma unroll
      for (int mt = 0; mt < 4; ++mt)
        af[mt] = *(const bf16x8*)(A2 + aJH[s] * 4096 + ((wt << 2) + mt) * 512 + quad * 128 + l15 * 8);
      #pragma unroll
      for (int nt = 0; nt < 2; ++nt)
        bfr[nt] = *(const bf16x8*)(bb + bJH[s] * 2048 + ((wc << 1) + nt) * 512 + quad * 128 + l15 * 8);
      #pragma unroll
      for (int mt = 0; mt < 4; ++mt)
        #pragma unroll
        for (int nt = 0; nt < 2; ++nt)
          acc[mt][nt] = __builtin_amdgcn_mfma_f32_16x16x32_bf16(af[mt], bfr[nt], acc[mt][nt], 0, 0, 0);
    }

    // eval: s = ee - 2*dot ; top-2 per token-slot (k ascending across ct, nt)
    #pragma unroll
    for (int nt = 0; nt < 2; ++nt) {
      int kcode = (ct << 6) + ((wc << 1) + nt) * 16 + l15;
      float eev = eeg[kcode];
      #pragma unroll
      for (int mt = 0; mt < 4; ++mt) {
        #pragma unroll
        for (int r = 0; r < 4; ++r) {
          float sv = fmaf(-2.0f, acc[mt][nt][r], eev);
          int slot = (mt << 2) + r;
          if (sv < bd[slot]) { sec[slot] = bd[slot]; bd[slot] = sv; bk[slot] = kcode; }
          else if (sv < sec[slot]) { sec[slot] = sv; }
        }
      }
    }
  }
  __syncthreads();   // compute done: A2/B2 dead, alias region live

  // top-2 merge across the 16 cols (lane&15), tie -> smaller k (validated r7 logic)
  #pragma unroll
  for (int m = 1; m <= 8; m <<= 1) {
    #pragma unroll
    for (int slot = 0; slot < 16; ++slot) {
      float obd = __shfl_xor(bd[slot], m, 64);
      int   obk = __shfl_xor(bk[slot], m, 64);
      float osec = __shfl_xor(sec[slot], m, 64);
      if (obd < bd[slot] || (obd == bd[slot] && obk < bk[slot])) {
        sec[slot] = fminf(bd[slot], osec); bd[slot] = obd; bk[slot] = obk;
      } else {
        sec[slot] = fminf(sec[slot], obd);
      }
    }
  }
  if (tid == 0) *ambN = 0;
  if (l15 == 0) {
    #pragma unroll
    for (int mt = 0; mt < 4; ++mt)
      #pragma unroll
      for (int r = 0; r < 4; ++r) {
        int t = (wt << 6) + (mt << 4) + (quad << 2) + r;
        int slot = (mt << 2) + r;
        mbd[(wc << 7) + t] = bd[slot]; mbk[(wc << 7) + t] = bk[slot]; msec[(wc << 7) + t] = sec[slot];
      }
  }
  __syncthreads();

  // merge code halves; flag ambiguous tokens for exact fixup
  if (tid < 128) {
    float b0 = mbd[tid], b1 = mbd[128 + tid];
    int k0 = mbk[tid], k1 = mbk[128 + tid];
    float fbd, fsec; int fbk;
    if (b1 < b0 || (b1 == b0 && k1 < k0)) { fbd = b1; fbk = k1; fsec = fminf(b0, msec[128 + tid]); }
    else                                  { fbd = b0; fbk = k0; fsec = fminf(msec[tid], b1); }
    skf[tid] = fbk;
    if (fsec - fbd <= EPSM) { int p = atomicAdd(ambN, 1); ambList[p] = tid; }
  }
  __syncthreads();

  // ---- exact fixup (rare): full scan with the bit-exact reference formula ----
  {
    int na = *ambN;
    for (int i = wv; i < na; i += 4) {
      int t = ambList[i];
      float zvl = z_e[(size_t)b * CHW + (size_t)lane * HW + s0 + t] / stdv[lane];
      float zz = 0.f;
      #pragma unroll
      for (int c = 0; c < 64; ++c) { float zc = __shfl(zvl, c, 64); zz = fmaf(zc, zc, zz); }
      float bdl = FLT_MAX; int bkl = 0;
      for (int kk = 0; kk < 16; ++kk) {
        int k = (lane << 4) + kk;              // ascending within lane chunk
        const float* er = emb + ((size_t)k << 6);
        float dot = 0.f;
        #pragma unroll
        for (int c4 = 0; c4 < 16; ++c4) {
          float4 ev = *(const float4*)(er + (c4 << 2));
          dot = fmaf(ev.x, __shfl(zvl, (c4 << 2) + 0, 64), dot);
          dot = fmaf(ev.y, __shfl(zvl, (c4 << 2) + 1, 64), dot);
          dot = fmaf(ev.z, __shfl(zvl, (c4 << 2) + 2, 64), dot);
          dot = fmaf(ev.w, __shfl(zvl, (c4 << 2) + 3, 64), dot);
        }
        float dd = (zz - 2.0f * dot) + eeg[k];
        if (dd < bdl) { bdl = dd; bkl = k; }
      }
      #pragma unroll
      for (int m = 1; m <= 32; m <<= 1) {
        float od = __shfl_xor(bdl, m, 64);
        int   ok = __shfl_xor(bkl, m, 64);
        if (od < bdl || (od == bdl && ok < bkl)) { bdl = od; bkl = ok; }
      }
      if (lane == 0) skf[t] = bkl;
    }
  }
  __syncthreads();

  if (tid < 128) out_idx[(blk << 7) + tid] = (float)skf[tid];

  // ---- epilogue: z recomputed bit-exactly from global, coalesced stores ----
  {
    int t = tid & 127;
    int ch = tid >> 7;
    int kq = skf[t];
    const float* eq = emb + ((size_t)kq << 6) + (ch << 5);
    const float* zb2 = z_e + (size_t)b * CHW + s0 + t;
    float* ob = out_zq + (size_t)b * CHW + s0 + t;
    float lsum = 0.f;
    #pragma unroll
    for (int jj = 0; jj < 32; ++jj) {
      int c = (ch << 5) + jj;
      float zv = zb2[(size_t)c * HW] / stdv[c];
      float e = eq[jj];
      float df = zv - e;
      lsum = fmaf(df, df, lsum);
      ob[(size_t)c * HW] = zv + (e - zv);
    }
    for (int o = 32; o > 0; o >>= 1) lsum += __shfl_down(lsum, o, 64);
    if (lane == 0) sred[wv] = lsum;
  }
  __syncthreads();
  if (tid == 0) loss_part[blk] = sred[0] + sred[1] + sred[2] + sred[3];
}

// ---------------- k_post: histogram + vq_loss + perplexity (validated) ----------------
__global__ __launch_bounds__(1024) void k_post(const float* __restrict__ loss_part,
                                               const float* __restrict__ out_idx,
                                               float* __restrict__ out_scalars) {
  __shared__ int hist[1024];
  __shared__ double rl[16], rh[16];
  int tid = threadIdx.x;
  hist[tid] = 0;
  __syncthreads();
  const float2* idx2 = (const float2*)out_idx;
  #pragma unroll
  for (int jj = 0; jj < 32; ++jj) {
    float2 v = idx2[tid + (jj << 10)];
    atomicAdd(&hist[(int)v.x], 1);
    atomicAdd(&hist[(int)v.y], 1);
  }
  __syncthreads();
  double ls = 0.0;
  if (tid < 512) ls = (double)loss_part[tid];
  float p = (float)hist[tid] * (1.0f / 65536.0f);
  float lg = logf(fmaxf(p, 1e-10f));
  double hs = (double)(p * lg);
  for (int o = 32; o > 0; o >>= 1) {
    ls += __shfl_down(ls, o, 64);
    hs += __shfl_down(hs, o, 64);
  }
  int wv = tid >> 6, ln = tid & 63;
  if (ln == 0) { rl[wv] = ls; rh[wv] = hs; }
  __syncthreads();
  if (tid == 0) {
    double L = 0.0, Hn = 0.0;
    #pragma unroll
    for (int w = 0; w < 16; ++w) { L += rl[w]; Hn += rh[w]; }
    float m = (float)(L / (double)NELEM);
    out_scalars[0] = 0.25f * m + m;
    out_scalars[1] = expf((float)(-Hn));
  }
}

extern "C" void kernel_launch(void* const* d_in, const int* in_sizes, int n_in,
                              void* d_out, int out_size, void* d_ws, size_t ws_size,
                              hipStream_t stream) {
  const float* z_e = (const float*)d_in[0];
  const float* emb = (const float*)d_in[1];
  float* ws = (float*)d_ws;
  float* loss_part = ws + WS_LOSS;
  float* stdv = ws + WS_STD;
  float* eeg = ws + WS_EE;
  unsigned short* e2g = (unsigned short*)(ws + WS_E2);   // 256 KB; ws use ~270 KB

  float* out = (float*)d_out;
  float* out_zq = out;                  // 4194304
  float* out_scalars = out + NELEM;     // vq_loss, perplexity
  float* out_idx = out + NELEM + 2;     // 65536 indices as float

  k_pre<<<80, 1024, 0, stream>>>(z_e, emb, stdv, e2g, eeg);
  k_vq<<<512, 256, 0, stream>>>(z_e, emb, stdv, eeg, e2g, out_zq, out_idx, loss_part);
  k_post<<<1, 1024, 0, stream>>>(loss_part, out_idx, out_scalars);
}

// Round 9
// 225.482 us; speedup vs baseline: 1.6137x; 1.6137x over previous
//
#include <hip/hip_runtime.h>
#include <math.h>
#include <float.h>

#define HW 4096
#define CHW 262144
#define NTOK 65536
#define NELEM 4194304

// ws float offsets
#define WS_LOSS 0        // 512 floats
#define WS_STD  512      // 64
#define WS_EE   576      // 1024 (exact fp32 row norms)
#define WS_E2   1600     // 131072 ushorts: codebook hi/lo, frag-contiguous per 64-code tile

#define EPSM 1.5e-4f     // ambiguity margin (~5x worst-case residual error)

typedef __attribute__((ext_vector_type(8))) short bf16x8;
typedef __attribute__((ext_vector_type(4))) float f32x4;

__device__ __forceinline__ unsigned short f2bf(float x) {
  unsigned u = __float_as_uint(x);
  u += 0x7FFFu + ((u >> 16) & 1u);
  return (unsigned short)(u >> 16);
}
__device__ __forceinline__ float bf2f(unsigned short h) {
  return __uint_as_float(((unsigned)h) << 16);
}
__device__ __forceinline__ void gload_lds16(const unsigned short* g, unsigned short* l) {
  __builtin_amdgcn_global_load_lds(
      (const __attribute__((address_space(1))) unsigned int*)g,
      (__attribute__((address_space(3))) unsigned int*)l, 16, 0, 0);
}

// ---------------- k_pre: blocks 0..63 std, 64..79 codebook decompose+swizzle ----------------
__global__ __launch_bounds__(1024) void k_pre(const float* __restrict__ z,
                                              const float* __restrict__ emb,
                                              float* __restrict__ stdv,
                                              unsigned short* __restrict__ e2g,
                                              float* __restrict__ eeg) {
  __shared__ double rs[16], rs2[16];
  int tid = threadIdx.x;
  int blk = blockIdx.x;
  if (blk < 64) {
    // per-channel std (ddof=1) — bit-identical to validated rounds
    int c = blk;
    double s = 0.0, s2 = 0.0;
    const float* base = z + c * HW;
    #pragma unroll 4
    for (int jj = 0; jj < 16; ++jj) {
      int f = tid + (jj << 10);
      int b = f >> 10, off4 = f & 1023;
      float4 v = *(const float4*)(base + (size_t)b * CHW + (off4 << 2));
      s  += (double)v.x + (double)v.y + (double)v.z + (double)v.w;
      s2 += (double)v.x * v.x + (double)v.y * v.y + (double)v.z * v.z + (double)v.w * v.w;
    }
    for (int o = 32; o > 0; o >>= 1) {
      s += __shfl_down(s, o, 64);
      s2 += __shfl_down(s2, o, 64);
    }
    int wv = tid >> 6, ln = tid & 63;
    if (ln == 0) { rs[wv] = s; rs2[wv] = s2; }
    __syncthreads();
    if (tid == 0) {
      double S = 0.0, S2 = 0.0;
      #pragma unroll
      for (int w = 0; w < 16; ++w) { S += rs[w]; S2 += rs2[w]; }
      const double N = (double)NTOK;
      double var = (S2 - S * S / N) / (N - 1.0);
      float sd = (float)sqrt(var);
      stdv[c] = fmaxf(sd, 1e-5f);
    }
  } else {
    // 64 codes/tile: bf16 hi|lo decompose into frag-contiguous tile layout
    // e2g[ct][jH(4)][cH(4)][jL(4)][cL(16)][8]  (ushort strides 2048/512/128/8)
    int ct = blk - 64;
    int k0 = ct << 6;
    int code = tid >> 4, c4 = tid & 15;
    float4 v = *(const float4*)(emb + (size_t)((k0 + code) << 6) + (c4 << 2));
    unsigned short h0 = f2bf(v.x), h1 = f2bf(v.y), h2 = f2bf(v.z), h3 = f2bf(v.w);
    unsigned short l0 = f2bf(v.x - bf2f(h0)), l1 = f2bf(v.y - bf2f(h1));
    unsigned short l2 = f2bf(v.z - bf2f(h2)), l3 = f2bf(v.w - bf2f(h3));
    int jL = (c4 >> 1) & 3;
    int e = (c4 & 1) << 2;
    int cH = code >> 4, cL = code & 15;
    size_t base = (size_t)ct * 8192 + cH * 512 + jL * 128 + cL * 8 + e;
    int jHh = c4 >> 3;          // hi chunks j=c4>>1 in 0..7 -> jH 0..1
    *(uint2*)(e2g + base + (size_t)jHh * 2048) =
        make_uint2((unsigned)h0 | ((unsigned)h1 << 16), (unsigned)h2 | ((unsigned)h3 << 16));
    *(uint2*)(e2g + base + (size_t)(2 + jHh) * 2048) =
        make_uint2((unsigned)l0 | ((unsigned)l1 << 16), (unsigned)l2 | ((unsigned)l3 << 16));
    if (tid < 64) {
      const float* er = emb + (size_t)((k0 + tid) << 6);
      float s = 0.f;
      #pragma unroll
      for (int c = 0; c < 64; ++c) s = fmaf(er[c], er[c], s);
      eeg[k0 + tid] = s;
    }
  }
}

// ---------------- main kernel: MFMA argmin (full hi/lo product) + cheap fixup ----------------
__global__ __launch_bounds__(256, 2) void k_vq(
    const float* __restrict__ z_e, const float* __restrict__ emb,
    const float* __restrict__ stdv, const float* __restrict__ eeg,
    const unsigned short* __restrict__ e2g,
    float* __restrict__ out_zq, float* __restrict__ out_idx,
    float* __restrict__ loss_part) {
  __shared__ unsigned short A2[16384];   // 32 KB: z hi/lo frag-contiguous
  __shared__ unsigned short B2[16384];   // 32 KB: two 16 KB code-tile buffers
  // scratch aliased onto A2 after the MFMA loop (A2 dead then):
  float* mbd = (float*)A2;               // [2*128]
  float* msec = (float*)A2 + 256;        // [2*128]
  int*   mbk = (int*)A2 + 512;           // [2*128]
  int*   skf = (int*)A2 + 768;           // [128]
  int*   ambList = (int*)A2 + 896;       // [128]
  int*   ambN = (int*)A2 + 1024;
  float* sred = (float*)A2 + 1028;       // [4]
  float* zf   = (float*)A2 + 1040;       // [64]  fixup z buffer
  float* fbd4 = (float*)A2 + 1104;       // [4]
  int*   fbk4 = (int*)A2 + 1108;         // [4]

  int tid = threadIdx.x;
  int lane = tid & 63;
  int wv = tid >> 6;
  int blk = blockIdx.x;            // 512 blocks
  int b = blk >> 5;
  int s0 = (blk & 31) << 7;        // 128 contiguous spatial positions

  // ---- stage A: normalize (IEEE div, bit-exact) + hi/lo decompose, frag layout ----
  // A2[jH(4)][tH(8)][jL(4)][tL(16)][8]: ushort strides 4096/512/128/8
  {
    int tok = tid >> 1, half = tid & 1;
    const float* zsrc = z_e + (size_t)b * CHW + (size_t)(half << 5) * HW + s0 + tok;
    unsigned hw_[16], lw_[16];
    #pragma unroll
    for (int cc = 0; cc < 32; ++cc) {
      float v = zsrc[(size_t)cc * HW] / stdv[(half << 5) + cc];
      unsigned short h = f2bf(v);
      unsigned short l = f2bf(v - bf2f(h));
      if (cc & 1) { hw_[cc >> 1] |= ((unsigned)h) << 16; lw_[cc >> 1] |= ((unsigned)l) << 16; }
      else        { hw_[cc >> 1] = h;                    lw_[cc >> 1] = l; }
    }
    int tH = tok >> 4, tL = tok & 15;
    int base = tH * 512 + tL * 8;
    #pragma unroll
    for (int jj = 0; jj < 4; ++jj) {
      *(uint4*)(A2 + half * 4096 + base + jj * 128) =
          make_uint4(hw_[4 * jj], hw_[4 * jj + 1], hw_[4 * jj + 2], hw_[4 * jj + 3]);
      *(uint4*)(A2 + (2 + half) * 4096 + base + jj * 128) =
          make_uint4(lw_[4 * jj], lw_[4 * jj + 1], lw_[4 * jj + 2], lw_[4 * jj + 3]);
    }
  }

  int quad = lane >> 4, l15 = lane & 15;
  int wt = wv >> 1, wc = wv & 1;

  float bd[16], sec[16];
  int bk[16];
  #pragma unroll
  for (int i = 0; i < 16; ++i) { bd[i] = FLT_MAX; sec[i] = FLT_MAX; bk[i] = 0; }

  // DMA tile 0 into buffer 0 (4 rounds x 1 KB per wave, lane*16B contiguous)
  {
    const unsigned short* gsrc = e2g + wv * 512 + (lane << 3);
    unsigned short* ldst = B2 + wv * 512;
    #pragma unroll
    for (int rr = 0; rr < 4; ++rr)
      gload_lds16(gsrc + rr * 2048, ldst + rr * 2048);
  }

  // slab plan: full product (zh+zl)*(eh+el), K'=256
  const int aJH[8] = {0, 1, 2, 3, 0, 1, 2, 3};
  const int bJH[8] = {0, 1, 0, 1, 2, 3, 2, 3};

  for (int ct = 0; ct < 16; ++ct) {
    __syncthreads();   // drains DMA(ct) [+A2 writes on first iter]; frees other buf
    const unsigned short* bb = B2 + (ct & 1) * 8192;
    if (ct < 15) {     // DMA next tile; overlaps compute, drained at next barrier
      const unsigned short* gsrc = e2g + (size_t)(ct + 1) * 8192 + wv * 512 + (lane << 3);
      unsigned short* ldst = B2 + ((ct + 1) & 1) * 8192 + wv * 512;
      #pragma unroll
      for (int rr = 0; rr < 4; ++rr)
        gload_lds16(gsrc + rr * 2048, ldst + rr * 2048);
    }

    f32x4 acc[4][2];
    #pragma unroll
    for (int mt = 0; mt < 4; ++mt) { acc[mt][0] = (f32x4)(0.f); acc[mt][1] = (f32x4)(0.f); }

    #pragma unroll
    for (int s = 0; s < 8; ++s) {
      bf16x8 af[4], bfr[2];
      #pragma unroll
      for (int mt = 0; mt < 4; ++mt)
        af[mt] = *(const bf16x8*)(A2 + aJH[s] * 4096 + ((wt << 2) + mt) * 512 + quad * 128 + l15 * 8);
      #pragma unroll
      for (int nt = 0; nt < 2; ++nt)
        bfr[nt] = *(const bf16x8*)(bb + bJH[s] * 2048 + ((wc << 1) + nt) * 512 + quad * 128 + l15 * 8);
      #pragma unroll
      for (int mt = 0; mt < 4; ++mt)
        #pragma unroll
        for (int nt = 0; nt < 2; ++nt)
          acc[mt][nt] = __builtin_amdgcn_mfma_f32_16x16x32_bf16(af[mt], bfr[nt], acc[mt][nt], 0, 0, 0);
    }

    // eval: s = ee - 2*dot ; top-2 per token-slot (k ascending across ct, nt)
    #pragma unroll
    for (int nt = 0; nt < 2; ++nt) {
      int kcode = (ct << 6) + ((wc << 1) + nt) * 16 + l15;
      float eev = eeg[kcode];
      #pragma unroll
      for (int mt = 0; mt < 4; ++mt) {
        #pragma unroll
        for (int r = 0; r < 4; ++r) {
          float sv = fmaf(-2.0f, acc[mt][nt][r], eev);
          int slot = (mt << 2) + r;
          if (sv < bd[slot]) { sec[slot] = bd[slot]; bd[slot] = sv; bk[slot] = kcode; }
          else if (sv < sec[slot]) { sec[slot] = sv; }
        }
      }
    }
  }
  __syncthreads();   // compute done: A2/B2 dead, alias region live

  // top-2 merge across the 16 cols (lane&15), tie -> smaller k (validated)
  #pragma unroll
  for (int m = 1; m <= 8; m <<= 1) {
    #pragma unroll
    for (int slot = 0; slot < 16; ++slot) {
      float obd = __shfl_xor(bd[slot], m, 64);
      int   obk = __shfl_xor(bk[slot], m, 64);
      float osec = __shfl_xor(sec[slot], m, 64);
      if (obd < bd[slot] || (obd == bd[slot] && obk < bk[slot])) {
        sec[slot] = fminf(bd[slot], osec); bd[slot] = obd; bk[slot] = obk;
      } else {
        sec[slot] = fminf(sec[slot], obd);
      }
    }
  }
  if (tid == 0) *ambN = 0;
  if (l15 == 0) {
    #pragma unroll
    for (int mt = 0; mt < 4; ++mt)
      #pragma unroll
      for (int r = 0; r < 4; ++r) {
        int t = (wt << 6) + (mt << 4) + (quad << 2) + r;
        int slot = (mt << 2) + r;
        mbd[(wc << 7) + t] = bd[slot]; mbk[(wc << 7) + t] = bk[slot]; msec[(wc << 7) + t] = sec[slot];
      }
  }
  __syncthreads();

  // merge code halves; flag ambiguous tokens for exact fixup
  if (tid < 128) {
    float b0 = mbd[tid], b1 = mbd[128 + tid];
    int k0 = mbk[tid], k1 = mbk[128 + tid];
    float fbd, fsec; int fbk;
    if (b1 < b0 || (b1 == b0 && k1 < k0)) { fbd = b1; fbk = k1; fsec = fminf(b0, msec[128 + tid]); }
    else                                  { fbd = b0; fbk = k0; fsec = fminf(msec[tid], b1); }
    skf[tid] = fbk;
    if (fsec - fbd <= EPSM) { int p = atomicAdd(ambN, 1); ambList[p] = tid; }
  }
  __syncthreads();

  // ---- exact fixup (rare): whole block on one token; thread = 4 codes ----
  // Bit-exact reference formula: seq-fmaf ascending c, (zz-2d)+ee, first-min.
  {
    int na = *ambN;
    for (int i = 0; i < na; ++i) {
      int t = ambList[i];
      if (tid < 64) zf[tid] = z_e[(size_t)b * CHW + (size_t)tid * HW + s0 + t] / stdv[tid];
      __syncthreads();
      const float4* zf4 = (const float4*)zf;
      const float* er0 = emb + ((size_t)(tid << 2) << 6);
      float zz = 0.f;
      float dot[4] = {0.f, 0.f, 0.f, 0.f};
      #pragma unroll
      for (int c4 = 0; c4 < 16; ++c4) {
        float4 zv = zf4[c4];
        zz = fmaf(zv.x, zv.x, zz); zz = fmaf(zv.y, zv.y, zz);
        zz = fmaf(zv.z, zv.z, zz); zz = fmaf(zv.w, zv.w, zz);
        #pragma unroll
        for (int j = 0; j < 4; ++j) {
          float4 ev = *(const float4*)(er0 + (j << 6) + (c4 << 2));
          dot[j] = fmaf(ev.x, zv.x, dot[j]);
          dot[j] = fmaf(ev.y, zv.y, dot[j]);
          dot[j] = fmaf(ev.z, zv.z, dot[j]);
          dot[j] = fmaf(ev.w, zv.w, dot[j]);
        }
      }
      float bdl = FLT_MAX; int bkl = 0;
      #pragma unroll
      for (int j = 0; j < 4; ++j) {       // ascending k within thread
        float dd = (zz - 2.0f * dot[j]) + eeg[(tid << 2) + j];
        if (dd < bdl) { bdl = dd; bkl = (tid << 2) + j; }
      }
      #pragma unroll
      for (int m = 1; m <= 32; m <<= 1) { // wave reduce, tie -> smaller k
        float od = __shfl_xor(bdl, m, 64);
        int   ok = __shfl_xor(bkl, m, 64);
        if (od < bdl || (od == bdl && ok < bkl)) { bdl = od; bkl = ok; }
      }
      if (lane == 0) { fbd4[wv] = bdl; fbk4[wv] = bkl; }
      __syncthreads();
      if (tid == 0) {                     // waves cover ascending k chunks
        float bb2 = fbd4[0]; int kk2 = fbk4[0];
        #pragma unroll
        for (int w = 1; w < 4; ++w)
          if (fbd4[w] < bb2 || (fbd4[w] == bb2 && fbk4[w] < kk2)) { bb2 = fbd4[w]; kk2 = fbk4[w]; }
        skf[t] = kk2;
      }
      __syncthreads();
    }
  }
  __syncthreads();

  if (tid < 128) out_idx[(blk << 7) + tid] = (float)skf[tid];

  // ---- epilogue: z recomputed bit-exactly from global, coalesced stores ----
  {
    int t = tid & 127;
    int ch = tid >> 7;
    int kq = skf[t];
    const float* eq = emb + ((size_t)kq << 6) + (ch << 5);
    const float* zb2 = z_e + (size_t)b * CHW + s0 + t;
    float* ob = out_zq + (size_t)b * CHW + s0 + t;
    float lsum = 0.f;
    #pragma unroll
    for (int jj = 0; jj < 32; ++jj) {
      int c = (ch << 5) + jj;
      float zv = zb2[(size_t)c * HW] / stdv[c];
      float e = eq[jj];
      float df = zv - e;
      lsum = fmaf(df, df, lsum);
      ob[(size_t)c * HW] = zv + (e - zv);
    }
    for (int o = 32; o > 0; o >>= 1) lsum += __shfl_down(lsum, o, 64);
    if (lane == 0) sred[wv] = lsum;
  }
  __syncthreads();
  if (tid == 0) loss_part[blk] = sred[0] + sred[1] + sred[2] + sred[3];
}

// ---------------- k_post: histogram + vq_loss + perplexity (validated) ----------------
__global__ __launch_bounds__(1024) void k_post(const float* __restrict__ loss_part,
                                               const float* __restrict__ out_idx,
                                               float* __restrict__ out_scalars) {
  __shared__ int hist[1024];
  __shared__ double rl[16], rh[16];
  int tid = threadIdx.x;
  hist[tid] = 0;
  __syncthreads();
  const float2* idx2 = (const float2*)out_idx;
  #pragma unroll
  for (int jj = 0; jj < 32; ++jj) {
    float2 v = idx2[tid + (jj << 10)];
    atomicAdd(&hist[(int)v.x], 1);
    atomicAdd(&hist[(int)v.y], 1);
  }
  __syncthreads();
  double ls = 0.0;
  if (tid < 512) ls = (double)loss_part[tid];
  float p = (float)hist[tid] * (1.0f / 65536.0f);
  float lg = logf(fmaxf(p, 1e-10f));
  double hs = (double)(p * lg);
  for (int o = 32; o > 0; o >>= 1) {
    ls += __shfl_down(ls, o, 64);
    hs += __shfl_down(hs, o, 64);
  }
  int wv = tid >> 6, ln = tid & 63;
  if (ln == 0) { rl[wv] = ls; rh[wv] = hs; }
  __syncthreads();
  if (tid == 0) {
    double L = 0.0, Hn = 0.0;
    #pragma unroll
    for (int w = 0; w < 16; ++w) { L += rl[w]; Hn += rh[w]; }
    float m = (float)(L / (double)NELEM);
    out_scalars[0] = 0.25f * m + m;
    out_scalars[1] = expf((float)(-Hn));
  }
}

extern "C" void kernel_launch(void* const* d_in, const int* in_sizes, int n_in,
                              void* d_out, int out_size, void* d_ws, size_t ws_size,
                              hipStream_t stream) {
  const float* z_e = (const float*)d_in[0];
  const float* emb = (const float*)d_in[1];
  float* ws = (float*)d_ws;
  float* loss_part = ws + WS_LOSS;
  float* stdv = ws + WS_STD;
  float* eeg = ws + WS_EE;
  unsigned short* e2g = (unsigned short*)(ws + WS_E2);   // 256 KB; ws use ~270 KB

  float* out = (float*)d_out;
  float* out_zq = out;                  // 4194304
  float* out_scalars = out + NELEM;     // vq_loss, perplexity
  float* out_idx = out + NELEM + 2;     // 65536 indices as float

  k_pre<<<80, 1024, 0, stream>>>(z_e, emb, stdv, e2g, eeg);
  k_vq<<<512, 256, 0, stream>>>(z_e, emb, stdv, eeg, e2g, out_zq, out_idx, loss_part);
  k_post<<<1, 1024, 0, stream>>>(loss_part, out_idx, out_scalars);
}

// Round 10
// 191.894 us; speedup vs baseline: 1.8962x; 1.1750x over previous
//
#include <hip/hip_runtime.h>
#include <math.h>
#include <float.h>

#define HW 4096
#define CHW 262144
#define NTOK 65536
#define NELEM 4194304

// ws float offsets
#define WS_LOSS 0        // 512 floats
#define WS_STD  512      // 64
#define WS_EE   576      // 1024 (exact fp32 row norms)
#define WS_E2   1600     // 131072 ushorts: codebook hi/lo, frag-contiguous per 64-code tile
#define WS_DONE 132672   // 1 int

#define EPSM 1.0e-4f     // certification margin (>=2x worst-case per-score error ~3e-5)

typedef __attribute__((ext_vector_type(8))) short bf16x8;
typedef __attribute__((ext_vector_type(4))) float f32x4;

__device__ __forceinline__ unsigned short f2bf(float x) {
  unsigned u = __float_as_uint(x);
  u += 0x7FFFu + ((u >> 16) & 1u);
  return (unsigned short)(u >> 16);
}
__device__ __forceinline__ float bf2f(unsigned short h) {
  return __uint_as_float(((unsigned)h) << 16);
}
__device__ __forceinline__ void gload_lds16(const unsigned short* g, unsigned short* l) {
  __builtin_amdgcn_global_load_lds(
      (const __attribute__((address_space(1))) unsigned int*)g,
      (__attribute__((address_space(3))) unsigned int*)l, 16, 0, 0);
}

// ---------------- k_pre: blocks 0..63 std, 64..79 codebook decompose+swizzle ----------------
__global__ __launch_bounds__(1024) void k_pre(const float* __restrict__ z,
                                              const float* __restrict__ emb,
                                              float* __restrict__ stdv,
                                              unsigned short* __restrict__ e2g,
                                              float* __restrict__ eeg,
                                              int* __restrict__ done) {
  __shared__ double rs[16], rs2[16];
  int tid = threadIdx.x;
  int blk = blockIdx.x;
  if (blk == 0 && tid == 0) *done = 0;   // re-init every launch (ws poisoned)
  if (blk < 64) {
    // per-channel std (ddof=1) — bit-identical to validated rounds
    int c = blk;
    double s = 0.0, s2 = 0.0;
    const float* base = z + c * HW;
    #pragma unroll 4
    for (int jj = 0; jj < 16; ++jj) {
      int f = tid + (jj << 10);
      int b = f >> 10, off4 = f & 1023;
      float4 v = *(const float4*)(base + (size_t)b * CHW + (off4 << 2));
      s  += (double)v.x + (double)v.y + (double)v.z + (double)v.w;
      s2 += (double)v.x * v.x + (double)v.y * v.y + (double)v.z * v.z + (double)v.w * v.w;
    }
    for (int o = 32; o > 0; o >>= 1) {
      s += __shfl_down(s, o, 64);
      s2 += __shfl_down(s2, o, 64);
    }
    int wv = tid >> 6, ln = tid & 63;
    if (ln == 0) { rs[wv] = s; rs2[wv] = s2; }
    __syncthreads();
    if (tid == 0) {
      double S = 0.0, S2 = 0.0;
      #pragma unroll
      for (int w = 0; w < 16; ++w) { S += rs[w]; S2 += rs2[w]; }
      const double N = (double)NTOK;
      double var = (S2 - S * S / N) / (N - 1.0);
      float sd = (float)sqrt(var);
      stdv[c] = fmaxf(sd, 1e-5f);
    }
  } else {
    // 64 codes/tile: bf16 hi|lo decompose into frag-contiguous tile layout
    // e2g[ct][jH(4)][cH(4)][jL(4)][cL(16)][8]  (ushort strides 2048/512/128/8)
    int ct = blk - 64;
    int k0 = ct << 6;
    int code = tid >> 4, c4 = tid & 15;
    float4 v = *(const float4*)(emb + (size_t)((k0 + code) << 6) + (c4 << 2));
    unsigned short h0 = f2bf(v.x), h1 = f2bf(v.y), h2 = f2bf(v.z), h3 = f2bf(v.w);
    unsigned short l0 = f2bf(v.x - bf2f(h0)), l1 = f2bf(v.y - bf2f(h1));
    unsigned short l2 = f2bf(v.z - bf2f(h2)), l3 = f2bf(v.w - bf2f(h3));
    int jL = (c4 >> 1) & 3;
    int e = (c4 & 1) << 2;
    int cH = code >> 4, cL = code & 15;
    size_t base = (size_t)ct * 8192 + cH * 512 + jL * 128 + cL * 8 + e;
    int jHh = c4 >> 3;
    *(uint2*)(e2g + base + (size_t)jHh * 2048) =
        make_uint2((unsigned)h0 | ((unsigned)h1 << 16), (unsigned)h2 | ((unsigned)h3 << 16));
    *(uint2*)(e2g + base + (size_t)(2 + jHh) * 2048) =
        make_uint2((unsigned)l0 | ((unsigned)l1 << 16), (unsigned)l2 | ((unsigned)l3 << 16));
    if (tid < 64) {
      const float* er = emb + (size_t)((k0 + tid) << 6);
      float s = 0.f;
      #pragma unroll
      for (int c = 0; c < 64; ++c) s = fmaf(er[c], er[c], s);
      eeg[k0 + tid] = s;
    }
  }
}

// ---------------- main kernel: MFMA argmin, reg-cached A, top-3 certify ----------------
__global__ __launch_bounds__(256, 2) void k_vq(
    const float* __restrict__ z_e, const float* __restrict__ emb,
    const float* __restrict__ stdv, const float* __restrict__ eeg,
    const unsigned short* __restrict__ e2g,
    float* __restrict__ out_zq, float* __restrict__ out_idx,
    float* __restrict__ loss_part, int* __restrict__ done,
    float* __restrict__ out_scalars) {
  __shared__ unsigned short A2[16384];   // 32 KB: z hi/lo frag-contiguous
  __shared__ unsigned short B2[16384];   // 32 KB: two 16 KB code-tile buffers
  __shared__ double rl[4], rh[4];
  __shared__ int lastFlag;
  // scalar scratch aliased onto A2 after the MFMA loop (A2 dead then):
  float* hs1 = (float*)A2;               // [2][128]
  float* hs2 = (float*)A2 + 256;
  float* hs3 = (float*)A2 + 512;
  int*   hk1 = (int*)A2 + 768;
  int*   hk2 = (int*)A2 + 1024;
  int*   skf = (int*)A2 + 1280;          // [128]
  int*   mk2f = (int*)A2 + 1408;         // [128]
  int*   pairL = (int*)A2 + 1536;        // [128]
  int*   fullL = (int*)A2 + 1664;        // [128]
  int*   cntB = (int*)A2 + 1792;
  int*   cntC = (int*)A2 + 1793;
  float* sred = (float*)A2 + 1796;       // [4]
  float* zf   = (float*)A2 + 1800;       // [64] (16B-aligned)
  float* fbd4 = (float*)A2 + 1864;
  int*   fbk4 = (int*)A2 + 1868;
  int*   hist = (int*)A2 + 1872;         // [1024] finalize

  int tid = threadIdx.x;
  int lane = tid & 63;
  int wv = tid >> 6;
  int blk = blockIdx.x;            // 512 blocks
  int b = blk >> 5;
  int s0 = (blk & 31) << 7;

  // ---- stage A: normalize (IEEE div, bit-exact) + hi/lo decompose, frag layout ----
  // A2[jH(4)][tH(8)][jL(4)][tL(16)][8]: ushort strides 4096/512/128/8
  {
    int tok = tid >> 1, half = tid & 1;
    const float* zsrc = z_e + (size_t)b * CHW + (size_t)(half << 5) * HW + s0 + tok;
    unsigned hw_[16], lw_[16];
    #pragma unroll
    for (int cc = 0; cc < 32; ++cc) {
      float v = zsrc[(size_t)cc * HW] / stdv[(half << 5) + cc];
      unsigned short h = f2bf(v);
      unsigned short l = f2bf(v - bf2f(h));
      if (cc & 1) { hw_[cc >> 1] |= ((unsigned)h) << 16; lw_[cc >> 1] |= ((unsigned)l) << 16; }
      else        { hw_[cc >> 1] = h;                    lw_[cc >> 1] = l; }
    }
    int tH = tok >> 4, tL = tok & 15;
    int base = tH * 512 + tL * 8;
    #pragma unroll
    for (int jj = 0; jj < 4; ++jj) {
      *(uint4*)(A2 + half * 4096 + base + jj * 128) =
          make_uint4(hw_[4 * jj], hw_[4 * jj + 1], hw_[4 * jj + 2], hw_[4 * jj + 3]);
      *(uint4*)(A2 + (2 + half) * 4096 + base + jj * 128) =
          make_uint4(lw_[4 * jj], lw_[4 * jj + 1], lw_[4 * jj + 2], lw_[4 * jj + 3]);
    }
  }

  int quad = lane >> 4, l15 = lane & 15;
  int wt = wv >> 1, wc = wv & 1;

  // DMA tile 0 into buffer 0
  {
    const unsigned short* gsrc = e2g + wv * 512 + (lane << 3);
    unsigned short* ldst = B2 + wv * 512;
    #pragma unroll
    for (int rr = 0; rr < 4; ++rr)
      gload_lds16(gsrc + rr * 2048, ldst + rr * 2048);
  }
  __syncthreads();   // A2 ready + DMA0 drained

  // A-fragments: loop-invariant -> cache in registers (16 b128, read once)
  bf16x8 afc[4][4];
  #pragma unroll
  for (int j = 0; j < 4; ++j)
    #pragma unroll
    for (int mt = 0; mt < 4; ++mt)
      afc[j][mt] = *(const bf16x8*)(A2 + j * 4096 + ((wt << 2) + mt) * 512 + quad * 128 + l15 * 8);

  // top-3 state per token-slot
  float ts1[16], ts2[16], ts3[16];
  int tk1[16], tk2[16];
  #pragma unroll
  for (int i = 0; i < 16; ++i) { ts1[i] = FLT_MAX; ts2[i] = FLT_MAX; ts3[i] = FLT_MAX; tk1[i] = 0; tk2[i] = 0; }

  // slab plan: full product (zh+zl)*(eh+el), K'=256
  const int aJH[8] = {0, 1, 2, 3, 0, 1, 2, 3};
  const int bJH[8] = {0, 1, 0, 1, 2, 3, 2, 3};

  #pragma unroll 1
  for (int ct = 0; ct < 16; ++ct) {
    const unsigned short* bb = B2 + (ct & 1) * 8192;
    if (ct < 15) {     // DMA next tile into other buffer; drained at end-of-iter barrier
      const unsigned short* gsrc = e2g + (size_t)(ct + 1) * 8192 + wv * 512 + (lane << 3);
      unsigned short* ldst = B2 + ((ct + 1) & 1) * 8192 + wv * 512;
      #pragma unroll
      for (int rr = 0; rr < 4; ++rr)
        gload_lds16(gsrc + rr * 2048, ldst + rr * 2048);
    }
    float ee0 = eeg[(ct << 6) + (wc << 5) + l15];
    float ee1 = eeg[(ct << 6) + (wc << 5) + 16 + l15];

    f32x4 acc[4][2];
    #pragma unroll
    for (int mt = 0; mt < 4; ++mt) { acc[mt][0] = (f32x4)(0.f); acc[mt][1] = (f32x4)(0.f); }

    #pragma unroll
    for (int s = 0; s < 8; ++s) {
      bf16x8 bfr[2];
      #pragma unroll
      for (int nt = 0; nt < 2; ++nt)
        bfr[nt] = *(const bf16x8*)(bb + bJH[s] * 2048 + ((wc << 1) + nt) * 512 + quad * 128 + l15 * 8);
      #pragma unroll
      for (int mt = 0; mt < 4; ++mt)
        #pragma unroll
        for (int nt = 0; nt < 2; ++nt)
          acc[mt][nt] = __builtin_amdgcn_mfma_f32_16x16x32_bf16(afc[aJH[s]][mt], bfr[nt], acc[mt][nt], 0, 0, 0);
    }

    // eval: s = ee - 2*dot ; top-3 insertion (k ascending across ct/nt within lane)
    #pragma unroll
    for (int nt = 0; nt < 2; ++nt) {
      int kc = (ct << 6) + (wc << 5) + (nt << 4) + l15;
      float eev = nt ? ee1 : ee0;
      #pragma unroll
      for (int mt = 0; mt < 4; ++mt) {
        #pragma unroll
        for (int r = 0; r < 4; ++r) {
          float sv = fmaf(-2.0f, acc[mt][nt][r], eev);
          int sl = (mt << 2) + r;
          bool lt1 = sv < ts1[sl];
          bool lt2 = sv < ts2[sl];
          bool lt3 = sv < ts3[sl];
          ts3[sl] = lt2 ? ts2[sl] : (lt3 ? sv : ts3[sl]);
          tk2[sl] = lt1 ? tk1[sl] : (lt2 ? kc : tk2[sl]);
          ts2[sl] = lt1 ? ts1[sl] : (lt2 ? sv : ts2[sl]);
          tk1[sl] = lt1 ? kc : tk1[sl];
          ts1[sl] = lt1 ? sv : ts1[sl];
        }
      }
    }
    if (ct < 15) __syncthreads();   // drain DMA(ct+1); all waves done with bb
  }
  __syncthreads();   // A2/B2 dead; alias region live

  // merge top-3 across the 16 cols (lane&15) via xor-shuffles; (s,k)-lex ties
  #pragma unroll
  for (int m = 1; m <= 8; m <<= 1) {
    #pragma unroll
    for (int sl = 0; sl < 16; ++sl) {
      float ob1 = __shfl_xor(ts1[sl], m, 64); int oq1 = __shfl_xor(tk1[sl], m, 64);
      float ob2 = __shfl_xor(ts2[sl], m, 64); int oq2 = __shfl_xor(tk2[sl], m, 64);
      float ob3 = __shfl_xor(ts3[sl], m, 64);
      bool t1 = (ts1[sl] < ob1) || (ts1[sl] == ob1 && tk1[sl] < oq1);
      float o1 = t1 ? ts1[sl] : ob1; int ok1 = t1 ? tk1[sl] : oq1;
      float aH = t1 ? ts2[sl] : ts1[sl]; int aHk = t1 ? tk2[sl] : tk1[sl]; float aH2 = t1 ? ts3[sl] : ts2[sl];
      float bH = t1 ? ob1 : ob2;         int bHk = t1 ? oq1 : oq2;         float bH2 = t1 ? ob2 : ob3;
      bool t2 = (aH < bH) || (aH == bH && aHk < bHk);
      float o2 = t2 ? aH : bH; int ok2 = t2 ? aHk : bHk;
      float aI = t2 ? aH2 : aH;
      float bI = t2 ? bH : bH2;
      ts1[sl] = o1; tk1[sl] = ok1; ts2[sl] = o2; tk2[sl] = ok2; ts3[sl] = fminf(aI, bI);
    }
  }
  if (tid == 0) { *cntB = 0; *cntC = 0; }
  if (l15 == 0) {
    #pragma unroll
    for (int mt = 0; mt < 4; ++mt)
      #pragma unroll
      for (int r = 0; r < 4; ++r) {
        int t = (wt << 6) + (mt << 4) + (quad << 2) + r;
        int sl = (mt << 2) + r;
        hs1[(wc << 7) + t] = ts1[sl]; hs2[(wc << 7) + t] = ts2[sl]; hs3[(wc << 7) + t] = ts3[sl];
        hk1[(wc << 7) + t] = tk1[sl]; hk2[(wc << 7) + t] = tk2[sl];
      }
  }
  __syncthreads();

  // cross-half merge + classification
  if (tid < 128) {
    float a1 = hs1[tid], a2 = hs2[tid], a3 = hs3[tid];
    int e1 = hk1[tid], e2 = hk2[tid];
    float b1 = hs1[128 + tid], b2 = hs2[128 + tid], b3 = hs3[128 + tid];
    int f1 = hk1[128 + tid], f2 = hk2[128 + tid];
    bool t1 = (a1 < b1) || (a1 == b1 && e1 < f1);
    float o1 = t1 ? a1 : b1; int ok1 = t1 ? e1 : f1;
    float aH = t1 ? a2 : a1; int aHk = t1 ? e2 : e1; float aH2 = t1 ? a3 : a2;
    float bH = t1 ? b1 : b2; int bHk = t1 ? f1 : f2; float bH2 = t1 ? b2 : b3;
    bool t2 = (aH < bH) || (aH == bH && aHk < bHk);
    float o2 = t2 ? aH : bH; int ok2 = t2 ? aHk : bHk;
    float o3 = fminf(t2 ? aH2 : aH, t2 ? bH : bH2);
    skf[tid] = ok1;
    mk2f[tid] = ok2;
    if (o2 - o1 <= EPSM) {
      if (o3 - o1 > EPSM) { int p = atomicAdd(cntB, 1); pairL[p] = tid; }
      else                { int p = atomicAdd(cntC, 1); fullL[p] = tid; }
    }
  }
  __syncthreads();

  int nB = *cntB, nC = *cntC;

  // ---- case B: exact pairwise compare {k1,k2}, one thread per token ----
  if (tid < nB) {
    int t = pairL[tid];
    int ka = skf[t], kb = mk2f[t];
    const float* za = z_e + (size_t)b * CHW + s0 + t;
    const float* ea = emb + ((size_t)ka << 6);
    const float* ebp = emb + ((size_t)kb << 6);
    float zz = 0.f, da = 0.f, db = 0.f;
    #pragma unroll
    for (int c = 0; c < 64; ++c) {
      float zv = za[(size_t)c * HW] / stdv[c];
      zz = fmaf(zv, zv, zz);
      da = fmaf(ea[c], zv, da);
      db = fmaf(ebp[c], zv, db);
    }
    float d1 = (zz - 2.0f * da) + eeg[ka];
    float d2 = (zz - 2.0f * db) + eeg[kb];
    if (d2 < d1 || (d2 == d1 && kb < ka)) skf[t] = kb;
  }
  __syncthreads();

  // ---- case C (rare): block-cooperative full scan, bit-exact formula ----
  for (int i = 0; i < nC; ++i) {
    int t = fullL[i];
    if (tid < 64) zf[tid] = z_e[(size_t)b * CHW + (size_t)tid * HW + s0 + t] / stdv[tid];
    __syncthreads();
    const float4* zf4 = (const float4*)zf;
    const float* er0 = emb + ((size_t)(tid << 2) << 6);
    float zz = 0.f;
    float dot[4] = {0.f, 0.f, 0.f, 0.f};
    #pragma unroll
    for (int c4 = 0; c4 < 16; ++c4) {
      float4 zv = zf4[c4];
      zz = fmaf(zv.x, zv.x, zz); zz = fmaf(zv.y, zv.y, zz);
      zz = fmaf(zv.z, zv.z, zz); zz = fmaf(zv.w, zv.w, zz);
      #pragma unroll
      for (int j = 0; j < 4; ++j) {
        float4 ev = *(const float4*)(er0 + (j << 6) + (c4 << 2));
        dot[j] = fmaf(ev.x, zv.x, dot[j]);
        dot[j] = fmaf(ev.y, zv.y, dot[j]);
        dot[j] = fmaf(ev.z, zv.z, dot[j]);
        dot[j] = fmaf(ev.w, zv.w, dot[j]);
      }
    }
    float bdl = FLT_MAX; int bkl = 0;
    #pragma unroll
    for (int j = 0; j < 4; ++j) {
      float dd = (zz - 2.0f * dot[j]) + eeg[(tid << 2) + j];
      if (dd < bdl) { bdl = dd; bkl = (tid << 2) + j; }
    }
    #pragma unroll
    for (int m = 1; m <= 32; m <<= 1) {
      float od = __shfl_xor(bdl, m, 64);
      int   ok = __shfl_xor(bkl, m, 64);
      if (od < bdl || (od == bdl && ok < bkl)) { bdl = od; bkl = ok; }
    }
    if (lane == 0) { fbd4[wv] = bdl; fbk4[wv] = bkl; }
    __syncthreads();
    if (tid == 0) {
      float bb2 = fbd4[0]; int kk2 = fbk4[0];
      #pragma unroll
      for (int w = 1; w < 4; ++w)
        if (fbd4[w] < bb2 || (fbd4[w] == bb2 && fbk4[w] < kk2)) { bb2 = fbd4[w]; kk2 = fbk4[w]; }
      skf[t] = kk2;
    }
    __syncthreads();
  }
  __syncthreads();

  if (tid < 128) out_idx[(blk << 7) + tid] = (float)skf[tid];

  // ---- epilogue: z recomputed bit-exactly from global, coalesced stores ----
  {
    int t = tid & 127;
    int ch = tid >> 7;
    int kq = skf[t];
    const float* eq = emb + ((size_t)kq << 6) + (ch << 5);
    const float* zb2 = z_e + (size_t)b * CHW + s0 + t;
    float* ob = out_zq + (size_t)b * CHW + s0 + t;
    float lsum = 0.f;
    #pragma unroll
    for (int jj = 0; jj < 32; ++jj) {
      int c = (ch << 5) + jj;
      float zv = zb2[(size_t)c * HW] / stdv[c];
      float e = eq[jj];
      float df = zv - e;
      lsum = fmaf(df, df, lsum);
      ob[(size_t)c * HW] = zv + (e - zv);
    }
    for (int o = 32; o > 0; o >>= 1) lsum += __shfl_down(lsum, o, 64);
    if (lane == 0) sred[wv] = lsum;
  }
  __syncthreads();

  // ---- fused finalize via done-counter (validated round-6 pattern) ----
  if (tid == 0) {
    loss_part[blk] = sred[0] + sred[1] + sred[2] + sred[3];
    __threadfence();
    int prev = atomicAdd(done, 1);
    lastFlag = (prev == 511);
  }
  __syncthreads();
  if (!lastFlag) return;

  #pragma unroll
  for (int jj = 0; jj < 4; ++jj) hist[tid + (jj << 8)] = 0;
  __syncthreads();
  {
    const float2* idx2 = (const float2*)out_idx;
    for (int i = tid; i < NTOK / 2; i += 256) {
      float2 v = idx2[i];
      atomicAdd(&hist[(int)v.x], 1);
      atomicAdd(&hist[(int)v.y], 1);
    }
  }
  __syncthreads();
  double ls = (double)loss_part[tid] + (double)loss_part[tid + 256];
  double hsum = 0.0;
  #pragma unroll
  for (int jj = 0; jj < 4; ++jj) {
    float p = (float)hist[tid + (jj << 8)] * (1.0f / 65536.0f);
    float lg = logf(fmaxf(p, 1e-10f));
    hsum += (double)(p * lg);
  }
  for (int o = 32; o > 0; o >>= 1) {
    ls += __shfl_down(ls, o, 64);
    hsum += __shfl_down(hsum, o, 64);
  }
  if (lane == 0) { rl[wv] = ls; rh[wv] = hsum; }
  __syncthreads();
  if (tid == 0) {
    double L = rl[0] + rl[1] + rl[2] + rl[3];
    double Hn = rh[0] + rh[1] + rh[2] + rh[3];
    float m = (float)(L / (double)NELEM);
    out_scalars[0] = 0.25f * m + m;
    out_scalars[1] = expf((float)(-Hn));
  }
}

extern "C" void kernel_launch(void* const* d_in, const int* in_sizes, int n_in,
                              void* d_out, int out_size, void* d_ws, size_t ws_size,
                              hipStream_t stream) {
  const float* z_e = (const float*)d_in[0];
  const float* emb = (const float*)d_in[1];
  float* ws = (float*)d_ws;
  float* loss_part = ws + WS_LOSS;
  float* stdv = ws + WS_STD;
  float* eeg = ws + WS_EE;
  unsigned short* e2g = (unsigned short*)(ws + WS_E2);
  int* done = (int*)(ws + WS_DONE);     // ws use ~531 KB

  float* out = (float*)d_out;
  float* out_zq = out;                  // 4194304
  float* out_scalars = out + NELEM;     // vq_loss, perplexity
  float* out_idx = out + NELEM + 2;     // 65536 indices as float

  k_pre<<<80, 1024, 0, stream>>>(z_e, emb, stdv, e2g, eeg, done);
  k_vq<<<512, 256, 0, stream>>>(z_e, emb, stdv, eeg, e2g, out_zq, out_idx,
                                loss_part, done, out_scalars);
}